// Round 2
// baseline (721.899 us; speedup 1.0000x reference)
//
#include <hip/hip_runtime.h>
#include <hip/hip_bf16.h>

#define NN 10000
#define NE 640000
#define SD 128
#define HD1 60
#define HD2 30
#define CONCAT 10003
#define ACT 10000

typedef unsigned int u32;

// ---------- dtype-flexible loads (flags decided at runtime by k_probe) ----------
__device__ __forceinline__ float loadF(const void* base, long idx, int bf) {
    if (bf) return __bfloat162float(((const __hip_bfloat16*)base)[idx]);
    return ((const float*)base)[idx];
}
__device__ __forceinline__ int loadI(const void* base, long idx, int i64) {
    if (i64) return (int)((const long long*)base)[idx];
    return ((const int*)base)[idx];
}

// flags[0] = edges are int64; flags[1] = floats are bf16
__global__ void k_probe(const void* __restrict__ edge, const void* __restrict__ wa,
                        int* __restrict__ flags) {
    if (threadIdx.x != 0 || blockIdx.x != 0) return;
    const int* e32 = (const int*)edge;
    int i64like = 0;
    for (int e = 0; e < 64; ++e) {
        int lo = e32[2 * e], hi = e32[2 * e + 1];
        if (hi == 0 && lo >= 0 && lo < NN) i64like++;
    }
    flags[0] = (i64like >= 56) ? 1 : 0;
    // bf16 detection: low 16 bits of each u32 word. If bf16 pairs, that's a
    // bf16 value of Wa ~ N(0, 1e-2) -> biased exponent ~113..124. If f32,
    // low 16 bits are uniform mantissa bits -> exponent field uniform.
    const u32* w = (const u32*)wa;
    int cnt = 0;
    for (int i = 0; i < 256; ++i) {
        u32 lo = w[i] & 0xFFFFu;
        int ex = (int)((lo >> 7) & 0xFF);
        if (ex >= 100 && ex <= 140) cnt++;
    }
    flags[1] = (cnt >= 128) ? 1 : 0;
}

__global__ void k_zero_int(int* p, int n) {
    int i = blockIdx.x * blockDim.x + threadIdx.x;
    if (i < n) p[i] = 0;
}

__global__ void k_deg(const void* __restrict__ edge, const int* __restrict__ flags,
                      int* __restrict__ deg) {
    int e = blockIdx.x * blockDim.x + threadIdx.x;
    int i64f = flags[0];
    if (e < NE) atomicAdd(&deg[loadI(edge, NE + e, i64f)], 1);
}

__global__ void k_dinv(const int* __restrict__ deg, float* __restrict__ dinv) {
    int i = blockIdx.x * blockDim.x + threadIdx.x;
    if (i < NN) dinv[i] = deg[i] > 0 ? rsqrtf((float)deg[i]) : 0.f;
}

// single-block exclusive scan of deg -> row_ptr[0..NN], row_ptr[NN]=NE
__global__ void k_scan(const int* __restrict__ deg, int* __restrict__ row_ptr) {
    __shared__ int s[1024];
    __shared__ int carry;
    if (threadIdx.x == 0) carry = 0;
    __syncthreads();
    for (int base = 0; base < NN; base += 1024) {
        int idx = base + threadIdx.x;
        int v = (idx < NN) ? deg[idx] : 0;
        s[threadIdx.x] = v;
        __syncthreads();
        for (int off = 1; off < 1024; off <<= 1) {
            int t = (threadIdx.x >= off) ? s[threadIdx.x - off] : 0;
            __syncthreads();
            s[threadIdx.x] += t;
            __syncthreads();
        }
        if (idx < NN) row_ptr[idx] = carry + s[threadIdx.x] - v;
        __syncthreads();
        if (threadIdx.x == 0) carry += s[1023];
        __syncthreads();
    }
    if (threadIdx.x == 0) row_ptr[NN] = carry;
}

__global__ void k_fill_init(const int* __restrict__ row_ptr, int* __restrict__ fill) {
    int i = blockIdx.x * blockDim.x + threadIdx.x;
    if (i < NN) fill[i] = row_ptr[i];
}

__global__ void k_fill(const void* __restrict__ edge, const int* __restrict__ flags,
                       const float* __restrict__ dinv, int* __restrict__ fill,
                       int* __restrict__ csr_col, float* __restrict__ csr_w) {
    int e = blockIdx.x * blockDim.x + threadIdx.x;
    int i64f = flags[0];
    if (e < NE) {
        int s = loadI(edge, e, i64f);
        int d = loadI(edge, NE + e, i64f);
        int p = atomicAdd(&fill[d], 1);
        csr_col[p] = s;
        csr_w[p] = -dinv[s] * dinv[d];
    }
}

__global__ void k_loadx(const void* __restrict__ in, const int* __restrict__ flags,
                        float* __restrict__ out, int n) {
    int i = blockIdx.x * blockDim.x + threadIdx.x;
    int bf = flags[1];
    if (i < n) out[i] = loadF(in, i, bf);
}

// y[i,d] = sum_{p in row i} csr_w[p] * x[csr_col[p]*D + d];  if T2MODE: y = 2*y - sub
template <int D, bool T2MODE>
__global__ void k_spmv(const int* __restrict__ row_ptr, const int* __restrict__ csr_col,
                       const float* __restrict__ csr_w, const float* __restrict__ x,
                       const float* __restrict__ sub, float* __restrict__ y) {
    int t = blockIdx.x * blockDim.x + threadIdx.x;
    if (t >= NN * D) return;
    int i = t / D, d = t % D;
    int beg = row_ptr[i], end = row_ptr[i + 1];
    float acc = 0.f;
    for (int p = beg; p < end; ++p) {
        acc += csr_w[p] * x[csr_col[p] * D + d];
    }
    y[t] = T2MODE ? 2.f * acc - sub[t] : acc;
}

// out[i,o] = tanh(b[o] + sum_j T0[i,j]W[0,j,o] + T1[i,j]W[1,j,o] + T2[i,j]W[2,j,o])
template <int DIN, int DOUT>
__global__ void k_cheb_out(const float* __restrict__ T0, const float* __restrict__ T1,
                           const float* __restrict__ T2, const void* __restrict__ W,
                           const void* __restrict__ b, const int* __restrict__ flags,
                           float* __restrict__ out) {
    int t = blockIdx.x * blockDim.x + threadIdx.x;
    int bf = flags[1];
    if (t >= NN * DOUT) return;
    int i = t / DOUT, o = t % DOUT;
    const float* t0 = T0 + i * DIN;
    const float* t1 = T1 + i * DIN;
    const float* t2 = T2 + i * DIN;
    float acc = loadF(b, o, bf);
    for (int j = 0; j < DIN; ++j) {
        acc += t0[j] * loadF(W, 0 * DIN * DOUT + j * DOUT + o, bf);
        acc += t1[j] * loadF(W, 1 * DIN * DOUT + j * DOUT + o, bf);
        acc += t2[j] * loadF(W, 2 * DIN * DOUT + j * DOUT + o, bf);
    }
    out[t] = tanhf(acc);
}

__global__ void k_tail(const void* s0, const void* s1, const void* s2,
                       const int* __restrict__ flags, float* __restrict__ state) {
    if (threadIdx.x == 0 && blockIdx.x == 0) {
        int bf = flags[1];
        state[10000] = loadF(s0, 0, bf);
        state[10001] = loadF(s1, 0, bf);
        state[10002] = loadF(s2, 0, bf);
    }
}

// row < ACT: logits row (Wa); row == ACT: critic (Wc).
__global__ void k_heads(const float* __restrict__ state, const void* __restrict__ Wa,
                        const void* __restrict__ ba, const void* __restrict__ Wc,
                        const void* __restrict__ bc, const int* __restrict__ flags,
                        void* __restrict__ out) {
    int row = blockIdx.x;
    int bf = flags[1];
    const void* wbase;
    long woff;
    float bias;
    if (row < ACT) {
        wbase = Wa;
        woff = (long)row * CONCAT;
        bias = loadF(ba, row, bf);
    } else {
        wbase = Wc;
        woff = 0;
        bias = loadF(bc, 0, bf);
    }
    float acc = 0.f;
    for (int i = threadIdx.x; i < CONCAT; i += blockDim.x)
        acc += state[i] * loadF(wbase, woff + i, bf);
    __shared__ float red[256];
    red[threadIdx.x] = acc;
    __syncthreads();
    for (int off = 128; off > 0; off >>= 1) {
        if (threadIdx.x < off) red[threadIdx.x] += red[threadIdx.x + off];
        __syncthreads();
    }
    if (threadIdx.x == 0) {
        float v = red[0] + bias;
        if (bf) ((__hip_bfloat16*)out)[row] = __float2bfloat16(v);
        else ((float*)out)[row] = v;
    }
}

extern "C" void kernel_launch(void* const* d_in, const int* in_sizes, int n_in,
                              void* d_out, int out_size, void* d_ws, size_t ws_size,
                              hipStream_t stream) {
    const void* x_in = d_in[0];
    const void* edge = d_in[1];
    const void* sc0 = d_in[2];
    const void* sc1 = d_in[3];
    const void* sc2 = d_in[4];
    const void* W1 = d_in[5];
    const void* b1 = d_in[6];
    const void* W2 = d_in[7];
    const void* b2 = d_in[8];
    const void* W3 = d_in[9];
    const void* b3 = d_in[10];
    const void* Wa = d_in[11];
    const void* ba = d_in[12];
    const void* Wc = d_in[13];
    const void* bc = d_in[14];

    char* p = (char*)d_ws;
    auto alloc = [&](size_t bytes) {
        char* r = p;
        p += (bytes + 255) & ~(size_t)255;
        return (void*)r;
    };
    int* flags = (int*)alloc(2 * 4);
    int* deg = (int*)alloc(NN * 4);
    float* dinv = (float*)alloc(NN * 4);
    int* row_ptr = (int*)alloc((NN + 1) * 4);
    int* fill = (int*)alloc(NN * 4);
    int* csr_col = (int*)alloc(NE * 4);
    float* csr_w = (float*)alloc(NE * 4);
    float* X0 = (float*)alloc((size_t)NN * SD * 4);
    float* T1 = (float*)alloc((size_t)NN * SD * 4);
    float* T2 = (float*)alloc((size_t)NN * SD * 4);
    float* H1f = (float*)alloc((size_t)NN * HD1 * 4);
    float* H2f = (float*)alloc((size_t)NN * HD2 * 4);
    float* state = (float*)alloc(CONCAT * 4);

    const int B = 256;
    k_probe<<<1, 64, 0, stream>>>(edge, Wa, flags);
    // graph prep
    k_zero_int<<<(NN + B - 1) / B, B, 0, stream>>>(deg, NN);
    k_deg<<<(NE + B - 1) / B, B, 0, stream>>>(edge, flags, deg);
    k_dinv<<<(NN + B - 1) / B, B, 0, stream>>>(deg, dinv);
    k_scan<<<1, 1024, 0, stream>>>(deg, row_ptr);
    k_fill_init<<<(NN + B - 1) / B, B, 0, stream>>>(row_ptr, fill);
    k_fill<<<(NE + B - 1) / B, B, 0, stream>>>(edge, flags, dinv, fill, csr_col, csr_w);
    k_loadx<<<(NN * SD + B - 1) / B, B, 0, stream>>>(x_in, flags, X0, NN * SD);

    // layer 1: 128 -> 60
    k_spmv<SD, false><<<(NN * SD + B - 1) / B, B, 0, stream>>>(row_ptr, csr_col, csr_w, X0, nullptr, T1);
    k_spmv<SD, true><<<(NN * SD + B - 1) / B, B, 0, stream>>>(row_ptr, csr_col, csr_w, T1, X0, T2);
    k_cheb_out<SD, HD1><<<(NN * HD1 + B - 1) / B, B, 0, stream>>>(X0, T1, T2, W1, b1, flags, H1f);

    // layer 2: 60 -> 30
    k_spmv<HD1, false><<<(NN * HD1 + B - 1) / B, B, 0, stream>>>(row_ptr, csr_col, csr_w, H1f, nullptr, T1);
    k_spmv<HD1, true><<<(NN * HD1 + B - 1) / B, B, 0, stream>>>(row_ptr, csr_col, csr_w, T1, H1f, T2);
    k_cheb_out<HD1, HD2><<<(NN * HD2 + B - 1) / B, B, 0, stream>>>(H1f, T1, T2, W2, b2, flags, H2f);

    // layer 3: 30 -> 1  (writes state[0..9999])
    k_spmv<HD2, false><<<(NN * HD2 + B - 1) / B, B, 0, stream>>>(row_ptr, csr_col, csr_w, H2f, nullptr, T1);
    k_spmv<HD2, true><<<(NN * HD2 + B - 1) / B, B, 0, stream>>>(row_ptr, csr_col, csr_w, T1, H2f, T2);
    k_cheb_out<HD2, 1><<<(NN + B - 1) / B, B, 0, stream>>>(H2f, T1, T2, W3, b3, flags, state);

    k_tail<<<1, 64, 0, stream>>>(sc0, sc1, sc2, flags, state);

    // heads: 10000 logit rows + 1 critic row
    k_heads<<<ACT + 1, 256, 0, stream>>>(state, Wa, ba, Wc, bc, flags, (void*)d_out);
}

// Round 3
// 567.378 us; speedup vs baseline: 1.2723x; 1.2723x over previous
//
#include <hip/hip_runtime.h>
#include <hip/hip_bf16.h>

#define NN 10000
#define NE 640000
#define SD 128
#define HD1 60
#define HD2 30
#define CONCAT 10003
#define ACT 10000

typedef unsigned int u32;
typedef unsigned short u16;
typedef u16 u16x8 __attribute__((ext_vector_type(8)));
typedef float f32x4 __attribute__((ext_vector_type(4)));

__device__ __forceinline__ float bf2f_bits(u16 u) {
    return __uint_as_float(((u32)u) << 16);
}
__device__ __forceinline__ float loadF(const void* base, long idx, int bf) {
    if (bf) return bf2f_bits(((const u16*)base)[idx]);
    return ((const float*)base)[idx];
}
__device__ __forceinline__ int loadI(const void* base, long idx, int i64) {
    if (i64) return (int)((const long long*)base)[idx];
    return ((const int*)base)[idx];
}

// block 0 thread 0: detect dtypes -> flags[0]=edge-int64, flags[1]=floats-bf16.
// all blocks: zero deg[].
__global__ void k_probe_zero(const void* __restrict__ edge, const void* __restrict__ wa,
                             int* __restrict__ flags, int* __restrict__ deg) {
    int i = blockIdx.x * blockDim.x + threadIdx.x;
    if (i < NN) deg[i] = 0;
    if (i == 0) {
        const int* e32 = (const int*)edge;
        int i64like = 0;
        for (int e = 0; e < 64; ++e) {
            int lo = e32[2 * e], hi = e32[2 * e + 1];
            if (hi == 0 && lo >= 0 && lo < NN) i64like++;
        }
        flags[0] = (i64like >= 56) ? 1 : 0;
        const u32* w = (const u32*)wa;
        int cnt = 0;
        for (int j = 0; j < 256; ++j) {
            u32 lo = w[j] & 0xFFFFu;
            int ex = (int)((lo >> 7) & 0xFF);
            if (ex >= 100 && ex <= 140) cnt++;
        }
        flags[1] = (cnt >= 128) ? 1 : 0;
    }
}

__global__ void k_deg(const void* __restrict__ edge, const int* __restrict__ flags,
                      int* __restrict__ deg) {
    int e = blockIdx.x * blockDim.x + threadIdx.x;
    int i64f = flags[0];
    if (e < NE) atomicAdd(&deg[loadI(edge, NE + e, i64f)], 1);
}

// 1 block / 1024 threads: dinv + exclusive scan (10 elems/thread) + fill init.
__global__ void k_scan_fused(const int* __restrict__ deg, float* __restrict__ dinv,
                             int* __restrict__ row_ptr, int* __restrict__ fill) {
    __shared__ int part[1024];
    int tid = threadIdx.x;
    int base = tid * 10;
    int loc[10];
    int s = 0;
    for (int j = 0; j < 10; ++j) {
        int idx = base + j;
        int d = (idx < NN) ? deg[idx] : 0;
        loc[j] = s;
        s += d;
        if (idx < NN) dinv[idx] = d > 0 ? rsqrtf((float)d) : 0.f;
    }
    part[tid] = s;
    __syncthreads();
    for (int off = 1; off < 1024; off <<= 1) {
        int t = (tid >= off) ? part[tid - off] : 0;
        __syncthreads();
        part[tid] += t;
        __syncthreads();
    }
    int prefix = (tid > 0) ? part[tid - 1] : 0;
    for (int j = 0; j < 10; ++j) {
        int idx = base + j;
        if (idx < NN) {
            int r = prefix + loc[j];
            row_ptr[idx] = r;
            fill[idx] = r;
        }
    }
    if (tid == 1023) row_ptr[NN] = part[1023];
}

__global__ void k_fill(const void* __restrict__ edge, const int* __restrict__ flags,
                       const float* __restrict__ dinv, int* __restrict__ fill,
                       int* __restrict__ csr_col, float* __restrict__ csr_w) {
    int e = blockIdx.x * blockDim.x + threadIdx.x;
    int i64f = flags[0];
    if (e < NE) {
        int s = loadI(edge, e, i64f);
        int d = loadI(edge, NE + e, i64f);
        int p = atomicAdd(&fill[d], 1);
        csr_col[p] = s;
        csr_w[p] = -dinv[s] * dinv[d];
    }
}

// vectorized input -> f32 (8 elems/thread). NN*SD = 1.28M, /8 = 160000 threads.
__global__ void k_loadx(const void* __restrict__ in, const int* __restrict__ flags,
                        float* __restrict__ out) {
    int i = blockIdx.x * blockDim.x + threadIdx.x;
    if (i >= NN * SD / 8) return;
    int bf = flags[1];
    float v[8];
    if (bf) {
        u16x8 u = ((const u16x8*)in)[i];
#pragma unroll
        for (int j = 0; j < 8; ++j) v[j] = bf2f_bits(u[j]);
    } else {
        f32x4 a = ((const f32x4*)in)[2 * i];
        f32x4 b = ((const f32x4*)in)[2 * i + 1];
#pragma unroll
        for (int j = 0; j < 4; ++j) { v[j] = a[j]; v[4 + j] = b[j]; }
    }
    f32x4* o = (f32x4*)(out + 8 * i);
    o[0] = (f32x4){v[0], v[1], v[2], v[3]};
    o[1] = (f32x4){v[4], v[5], v[6], v[7]};
}

// D=128 spmv, float4 per lane: 32 quads per row.
template <bool T2MODE>
__global__ void k_spmv4_128(const int* __restrict__ row_ptr, const int* __restrict__ csr_col,
                            const float* __restrict__ csr_w, const float* __restrict__ x,
                            const float* __restrict__ sub, float* __restrict__ y) {
    int t = blockIdx.x * blockDim.x + threadIdx.x;
    if (t >= NN * 32) return;
    int i = t >> 5, q = t & 31;
    int beg = row_ptr[i], end = row_ptr[i + 1];
    f32x4 acc = {0.f, 0.f, 0.f, 0.f};
    for (int p = beg; p < end; ++p) {
        float wv = csr_w[p];
        f32x4 xv = *(const f32x4*)(x + csr_col[p] * 128 + q * 4);
        acc += wv * xv;
    }
    f32x4 res;
    if (T2MODE) {
        f32x4 sv = *(const f32x4*)(sub + i * 128 + q * 4);
        res = 2.f * acc - sv;
    } else {
        res = acc;
    }
    *(f32x4*)(y + i * 128 + q * 4) = res;
}

// generic scalar spmv for D=60/30
template <int D, bool T2MODE>
__global__ void k_spmv(const int* __restrict__ row_ptr, const int* __restrict__ csr_col,
                       const float* __restrict__ csr_w, const float* __restrict__ x,
                       const float* __restrict__ sub, float* __restrict__ y) {
    int t = blockIdx.x * blockDim.x + threadIdx.x;
    if (t >= NN * D) return;
    int i = t / D, d = t % D;
    int beg = row_ptr[i], end = row_ptr[i + 1];
    float acc = 0.f;
    for (int p = beg; p < end; ++p) {
        acc += csr_w[p] * x[csr_col[p] * D + d];
    }
    y[t] = T2MODE ? 2.f * acc - sub[t] : acc;
}

// out[i,o] = tanh(b[o] + sum_j T0[i,j]W[0,j,o] + T1[i,j]W[1,j,o] + T2[i,j]W[2,j,o])
// TAIL: thread 0 also writes state[10000..10002] from scalars.
template <int DIN, int DOUT, bool TAIL>
__global__ void k_cheb_out(const float* __restrict__ T0, const float* __restrict__ T1,
                           const float* __restrict__ T2, const void* __restrict__ W,
                           const void* __restrict__ b, const int* __restrict__ flags,
                           float* __restrict__ out, const void* s0, const void* s1,
                           const void* s2) {
    int t = blockIdx.x * blockDim.x + threadIdx.x;
    int bf = flags[1];
    if (TAIL && t == 0) {
        out[10000] = loadF(s0, 0, bf);
        out[10001] = loadF(s1, 0, bf);
        out[10002] = loadF(s2, 0, bf);
    }
    if (t >= NN * DOUT) return;
    int i = t / DOUT, o = t % DOUT;
    const float* t0 = T0 + i * DIN;
    const float* t1 = T1 + i * DIN;
    const float* t2 = T2 + i * DIN;
    float acc = loadF(b, o, bf);
    for (int j = 0; j < DIN; ++j) {
        acc += t0[j] * loadF(W, 0 * DIN * DOUT + j * DOUT + o, bf);
        acc += t1[j] * loadF(W, 1 * DIN * DOUT + j * DOUT + o, bf);
        acc += t2[j] * loadF(W, 2 * DIN * DOUT + j * DOUT + o, bf);
    }
    out[t] = tanhf(acc);
}

// one wave per output row; vectorized 16B weight loads with alignment prologue.
__global__ void k_heads(const float* __restrict__ state, const void* __restrict__ Wa,
                        const void* __restrict__ ba, const void* __restrict__ Wc,
                        const void* __restrict__ bc, const int* __restrict__ flags,
                        void* __restrict__ out) {
    int wid = (blockIdx.x * blockDim.x + threadIdx.x) >> 6;
    int lane = threadIdx.x & 63;
    if (wid > ACT) return;
    int bf = flags[1];
    int row = wid;
    long base = (row < ACT) ? (long)row * CONCAT : 0;
    const void* wb = (row < ACT) ? Wa : Wc;
    float acc = 0.f;
    if (bf) {
        const u16* w = (const u16*)wb + base;
        int k = (int)((16 - ((2 * base) & 15)) & 15) >> 1;  // elems to 16B alignment
        for (int i = lane; i < k; i += 64) acc += state[i] * bf2f_bits(w[i]);
        int nv = (CONCAT - k) >> 3;
        const u16x8* wv = (const u16x8*)(w + k);
        for (int v = lane; v < nv; v += 64) {
            u16x8 ww = wv[v];
            int ib = k + v * 8;
#pragma unroll
            for (int j = 0; j < 8; ++j) acc += state[ib + j] * bf2f_bits(ww[j]);
        }
        for (int i = k + nv * 8 + lane; i < CONCAT; i += 64)
            acc += state[i] * bf2f_bits(w[i]);
    } else {
        const float* w = (const float*)wb + base;
        int k = (int)((16 - ((4 * base) & 15)) & 15) >> 2;
        for (int i = lane; i < k; i += 64) acc += state[i] * w[i];
        int nv = (CONCAT - k) >> 2;
        const f32x4* wv = (const f32x4*)(w + k);
        for (int v = lane; v < nv; v += 64) {
            f32x4 ww = wv[v];
            int ib = k + v * 4;
#pragma unroll
            for (int j = 0; j < 4; ++j) acc += state[ib + j] * ww[j];
        }
        for (int i = k + nv * 4 + lane; i < CONCAT; i += 64)
            acc += state[i] * w[i];
    }
#pragma unroll
    for (int o = 32; o > 0; o >>= 1) acc += __shfl_xor(acc, o);
    if (lane == 0) {
        float bias = (row < ACT) ? loadF(ba, row, bf) : loadF(bc, 0, bf);
        float v = acc + bias;
        if (bf) ((__hip_bfloat16*)out)[row] = __float2bfloat16(v);
        else ((float*)out)[row] = v;
    }
}

extern "C" void kernel_launch(void* const* d_in, const int* in_sizes, int n_in,
                              void* d_out, int out_size, void* d_ws, size_t ws_size,
                              hipStream_t stream) {
    const void* x_in = d_in[0];
    const void* edge = d_in[1];
    const void* sc0 = d_in[2];
    const void* sc1 = d_in[3];
    const void* sc2 = d_in[4];
    const void* W1 = d_in[5];
    const void* b1 = d_in[6];
    const void* W2 = d_in[7];
    const void* b2 = d_in[8];
    const void* W3 = d_in[9];
    const void* b3 = d_in[10];
    const void* Wa = d_in[11];
    const void* ba = d_in[12];
    const void* Wc = d_in[13];
    const void* bc = d_in[14];

    char* p = (char*)d_ws;
    auto alloc = [&](size_t bytes) {
        char* r = p;
        p += (bytes + 255) & ~(size_t)255;
        return (void*)r;
    };
    int* flags = (int*)alloc(2 * 4);
    int* deg = (int*)alloc(NN * 4);
    float* dinv = (float*)alloc(NN * 4);
    int* row_ptr = (int*)alloc((NN + 1) * 4);
    int* fill = (int*)alloc(NN * 4);
    int* csr_col = (int*)alloc(NE * 4);
    float* csr_w = (float*)alloc(NE * 4);
    float* X0 = (float*)alloc((size_t)NN * SD * 4);
    float* T1 = (float*)alloc((size_t)NN * SD * 4);
    float* T2 = (float*)alloc((size_t)NN * SD * 4);
    float* H1f = (float*)alloc((size_t)NN * HD1 * 4);
    float* H2f = (float*)alloc((size_t)NN * HD2 * 4);
    float* state = (float*)alloc(CONCAT * 4);

    const int B = 256;
    k_probe_zero<<<(NN + B - 1) / B, B, 0, stream>>>(edge, Wa, flags, deg);
    k_deg<<<(NE + B - 1) / B, B, 0, stream>>>(edge, flags, deg);
    k_scan_fused<<<1, 1024, 0, stream>>>(deg, dinv, row_ptr, fill);
    k_fill<<<(NE + B - 1) / B, B, 0, stream>>>(edge, flags, dinv, fill, csr_col, csr_w);
    k_loadx<<<(NN * SD / 8 + B - 1) / B, B, 0, stream>>>(x_in, flags, X0);

    // layer 1: 128 -> 60
    k_spmv4_128<false><<<(NN * 32 + B - 1) / B, B, 0, stream>>>(row_ptr, csr_col, csr_w, X0, nullptr, T1);
    k_spmv4_128<true><<<(NN * 32 + B - 1) / B, B, 0, stream>>>(row_ptr, csr_col, csr_w, T1, X0, T2);
    k_cheb_out<SD, HD1, false><<<(NN * HD1 + B - 1) / B, B, 0, stream>>>(X0, T1, T2, W1, b1, flags, H1f, nullptr, nullptr, nullptr);

    // layer 2: 60 -> 30
    k_spmv<HD1, false><<<(NN * HD1 + B - 1) / B, B, 0, stream>>>(row_ptr, csr_col, csr_w, H1f, nullptr, T1);
    k_spmv<HD1, true><<<(NN * HD1 + B - 1) / B, B, 0, stream>>>(row_ptr, csr_col, csr_w, T1, H1f, T2);
    k_cheb_out<HD1, HD2, false><<<(NN * HD2 + B - 1) / B, B, 0, stream>>>(H1f, T1, T2, W2, b2, flags, H2f, nullptr, nullptr, nullptr);

    // layer 3: 30 -> 1 (+ tail scalars into state)
    k_spmv<HD2, false><<<(NN * HD2 + B - 1) / B, B, 0, stream>>>(row_ptr, csr_col, csr_w, H2f, nullptr, T1);
    k_spmv<HD2, true><<<(NN * HD2 + B - 1) / B, B, 0, stream>>>(row_ptr, csr_col, csr_w, T1, H2f, T2);
    k_cheb_out<HD2, 1, true><<<(NN + B - 1) / B, B, 0, stream>>>(H2f, T1, T2, W3, b3, flags, state, sc0, sc1, sc2);

    // heads: one wave per row, 10001 rows
    int waves = ACT + 1;
    k_heads<<<(waves * 64 + B - 1) / B, B, 0, stream>>>(state, Wa, ba, Wc, bc, flags, d_out);
}